// Round 8
// baseline (627.133 us; speedup 1.0000x reference)
//
#include <hip/hip_runtime.h>
#include <math.h>

#define T_   4
#define B_   32
#define C_   512
#define N_   196
#define TB_  128
#define M_   25088          // TB_*N_
#define BNP_ 6272           // B_*N_  (t-plane stride in bn-space)
#define OUT1_ 12845056      // T_*B_*C_*N_

typedef unsigned short ushort_t;
typedef __attribute__((ext_vector_type(8)))  __bf16 bf16x8;
typedef __attribute__((ext_vector_type(16))) float  f32x16;

__device__ __forceinline__ ushort_t f2bf(float f) {
    unsigned int u = __float_as_uint(f);
    u = u + 0x7FFFu + ((u >> 16) & 1u);      // RN-even
    return (ushort_t)(u >> 16);
}
__device__ __forceinline__ float bf2f(ushort_t h) {
    return __uint_as_float(((unsigned int)h) << 16);
}

#define GL2LDS(gp, lp) \
    __builtin_amdgcn_global_load_lds((const __attribute__((address_space(1))) void*)(gp), \
                                     (__attribute__((address_space(3))) void*)(lp), 16, 0, 0)

// ---------------------------------------------------------------------------
// K0+K1 merged: blocks [0,3072) = prep; blocks [3072,4096) = lifx.
// (unchanged from round 7 — passed)
// ---------------------------------------------------------------------------
__global__ __launch_bounds__(256)
void prep_lifx_kernel(
    const float* __restrict__ qw, const float* __restrict__ kw,
    const float* __restrict__ vw, const float* __restrict__ ow,
    const float* __restrict__ qg, const float* __restrict__ qb, const float* __restrict__ qm, const float* __restrict__ qv,
    const float* __restrict__ kg, const float* __restrict__ kb, const float* __restrict__ km, const float* __restrict__ kvr,
    const float* __restrict__ vg, const float* __restrict__ vb, const float* __restrict__ vm, const float* __restrict__ vv,
    const float* __restrict__ og, const float* __restrict__ ob, const float* __restrict__ om, const float* __restrict__ ov,
    const float* __restrict__ obias,
    ushort_t* __restrict__ wsplit, ushort_t* __restrict__ osplit,
    float* __restrict__ scale_qkv, float* __restrict__ shift_qkv,
    float* __restrict__ scale_o,   float* __restrict__ shift_o,
    float* __restrict__ kvpart,
    const float* __restrict__ x, ushort_t* __restrict__ xs)
{
    __shared__ ushort_t tile[64 * 66];
    const int bid = blockIdx.x;
    const int tid = threadIdx.x;

    if (bid < 3072) {
        int i = bid * 256 + tid;                 // [0, 1536*512)
        int d = i >> 9, c = i & 511;
        const float* src = (d < 512) ? qw : (d < 1024) ? kw : vw;
        float wv = src[(d & 511) * 512 + c];
        ushort_t h = f2bf(wv);
        float r1 = wv - bf2f(h);
        ushort_t mm = f2bf(r1);
        wsplit[((size_t)d * 2 + 0) * 512 + c] = h;
        wsplit[((size_t)d * 2 + 1) * 512 + c] = mm;
        if (d < 512)
            osplit[(size_t)d * 512 + c] = f2bf(ow[d * 512 + c]);

        if (i < 3 * C_) {
            int p = i >> 9, dl = i & 511;
            const float* g = (p == 0) ? qg : (p == 1) ? kg : vg;
            const float* b = (p == 0) ? qb : (p == 1) ? kb : vb;
            const float* m = (p == 0) ? qm : (p == 1) ? km : vm;
            const float* r = (p == 0) ? qv : (p == 1) ? kvr : vv;
            float sc = g[dl] / sqrtf(r[dl] + 1e-5f);
            scale_qkv[i] = sc;
            shift_qkv[i] = b[dl] - m[dl] * sc;
        }
        if (i < C_) {
            float sc = og[i] / sqrtf(ov[i] + 1e-5f);
            scale_o[i] = sc;
            shift_o[i] = ob[i] - om[i] * sc + obias[i] * sc;
        }
        if (i < TB_ * C_) kvpart[i] = 0.f;
        return;
    }

    const int l = bid - 3072;                    // [0, 1024)
    const int n0 = (l & 3) * 64;
    const int c0 = ((l >> 2) & 7) * 64;
    const int b  = l >> 5;
    const int j = tid & 63, w = tid >> 6;
    const bool nok = (n0 + j) < N_;
    float v[16];
#pragma unroll
    for (int r = 0; r < 16; ++r) v[r] = 0.f;
    for (int t = 0; t < T_; ++t) {
        const float* xb = x + ((size_t)((t * B_ + b) * C_ + c0)) * N_ + n0 + j;
#pragma unroll
        for (int r = 0; r < 16; ++r) {
            int i = w * 16 + r;
            float xv = nok ? xb[(size_t)i * N_] : 0.f;
            v[r] = v[r] + (xv - v[r]) * 0.5f;
            bool s = (v[r] >= 1.0f);
            tile[j * 66 + i] = s ? 0x3F80 : 0;
            if (s) v[r] = 0.f;
        }
        __syncthreads();
#pragma unroll
        for (int p = 0; p < 2; ++p) {
            int w2 = tid + p * 256;
            int jj = w2 >> 3, ck = w2 & 7;
            if (n0 + jj < N_) {
                const unsigned int* src = reinterpret_cast<const unsigned int*>(&tile[jj * 66 + ck * 8]);
                uint4 dv; dv.x = src[0]; dv.y = src[1]; dv.z = src[2]; dv.w = src[3];
                size_t mp = (size_t)(b * N_ + n0 + jj) * 4 + t;      // permuted row
                *reinterpret_cast<uint4*>(&xs[mp * 512 + c0 + ck * 8]) = dv;
            }
        }
        __syncthreads();
    }
}

// ---------------------------------------------------------------------------
// K2 (round 8): fused qkv GEMM + kv-reduction. One block owns (m-tile 256,
// dl-slice 128) and runs the PROVEN round-1 2-phase K-loop three times
// (plane loop p = q,k,v; only d0 changes). Epilogues:
//   p=0 (q): BN+LIF -> write q spike plane (out_gemm's input) [unchanged]
//   p=1 (k): BN+LIF -> spikes kept ONLY as a 4KB LDS bitmask via __ballot
//            (lanes 0-31 = bn-even row, 32-63 = bn-odd; 1 ballot = 2 words)
//   p=2 (v): BN+LIF -> write vh (out2) + AND with k-bits -> in-register
//            partial sums per (t, b-slot) -> LDS cnt -> global float
//            atomicAdd into kvpart (integer-valued, <=196 -> exact).
// k/v spike planes are never written (-51MB W); kv_part kernel deleted
// (-51MB R, -1 launch). X tile re-read 3x per block = L2-resident re-hits.
// Grid 392 = 98 m_t x 4 d_t, bijective XCD swizzle (392 = 8*49), m-major
// per XCD. LDS 72KB -> 2 blocks/CU; all 392 blocks co-resident (no tail).
// ---------------------------------------------------------------------------
__global__ __launch_bounds__(512, 4)
void qkv_gemm_lif(const ushort_t* __restrict__ W, const ushort_t* __restrict__ X,
                  const float* __restrict__ scale, const float* __restrict__ shift,
                  ushort_t* __restrict__ qspk, float* __restrict__ out2,
                  float* __restrict__ kvpart)
{
    const int id = blockIdx.x;                   // [0, 392)
    const int xcd = id & 7, local = id >> 3;     // local in [0,49)
    const int g = xcd * 49 + local;              // bijective remap
    const int m_t = g >> 2, d_t = g & 3;         // m_t < 98, d_t < 4
    const int m0 = m_t * 256;                    // m' base (256-tile)
    const int dl0 = d_t * 128;                   // channel slice [0,512)

    __shared__ ushort_t Xs[2][16 * 512];  // 32KB: 16 chunks [mb(8)][ks(2)]
    __shared__ ushort_t Ws[2][16 * 512];  // 32KB: 16 chunks [s(2)][db(4)][ks(2)]
    __shared__ unsigned kmask[1024];      // 4KB: [bn_local(64)][t(4)][dlblk(4)]
    __shared__ int      cnt[1024];        // 4KB: [t(4)][bslot(2)][dl(128)]

    const int tid = threadIdx.x, wid = tid >> 6, lane = tid & 63;
    const int mw = (wid & 3) * 64, dw = (wid >> 2) * 64;
    const int row32 = lane & 31, khalf = lane >> 5;

    const int bn0 = m_t * 64;                    // linear bn base of this tile
    const int b0 = bn0 / N_;
    const int bsplit = (b0 + 1) * N_ - bn0;      // bn_local where b increments

    // stage one K-tile into buffer buf for plane base d0g (round-1 verbatim)
    auto STAGE = [&](int buf, int k0, int d0g) {
        {   int q = wid, mb = q >> 1, ks = q & 1;
            const ushort_t* gp = X + (size_t)(m0 + mb * 32 + row32) * 512 + k0 + ks * 16 + khalf * 8;
            GL2LDS(gp, &Xs[buf][q * 512]);
        }
        {   int q = wid + 8, mb = q >> 1, ks = q & 1;
            const ushort_t* gp = X + (size_t)(m0 + mb * 32 + row32) * 512 + k0 + ks * 16 + khalf * 8;
            GL2LDS(gp, &Xs[buf][q * 512]);
        }
        {   int q = wid, s = q >> 3, rem = q & 7, db = rem >> 1, ks = rem & 1;
            const ushort_t* gp = W + ((size_t)(d0g + db * 32 + row32) * 2 + s) * 512 + k0 + ks * 16 + khalf * 8;
            GL2LDS(gp, &Ws[buf][q * 512]);
        }
        {   int q = wid + 8, s = q >> 3, rem = q & 7, db = rem >> 1, ks = rem & 1;
            const ushort_t* gp = W + ((size_t)(d0g + db * 32 + row32) * 2 + s) * 512 + k0 + ks * 16 + khalf * 8;
            GL2LDS(gp, &Ws[buf][q * 512]);
        }
    };

    for (int p = 0; p < 3; ++p) {
        const int d0g = p * 512 + dl0;           // global d base for this plane
        f32x16 acc[2][2] = {};                   // [i: m-block32][j: d-block32]

        // ----- round-1 2-phase double-buffered K-loop (verbatim) -----
        STAGE(0, 0, d0g);
        __syncthreads();
        int cur = 0;
        for (int it = 0; it < 16; ++it) {
            if (it < 15) STAGE(cur ^ 1, (it + 1) * 32, d0g);

            __builtin_amdgcn_s_setprio(1);
#pragma unroll
            for (int ks = 0; ks < 2; ++ks) {
                bf16x8 xfr[2];
#pragma unroll
                for (int i = 0; i < 2; ++i)
                    xfr[i] = *reinterpret_cast<const bf16x8*>(
                        &Xs[cur][(((mw >> 5) + i) * 2 + ks) * 512 + lane * 8]);
#pragma unroll
                for (int s = 0; s < 2; ++s)
#pragma unroll
                    for (int j = 0; j < 2; ++j) {
                        bf16x8 wfr = *reinterpret_cast<const bf16x8*>(
                            &Ws[cur][(s * 8 + ((dw >> 5) + j) * 2 + ks) * 512 + lane * 8]);
#pragma unroll
                        for (int i = 0; i < 2; ++i)
                            acc[i][j] = __builtin_amdgcn_mfma_f32_32x32x16_bf16(xfr[i], wfr, acc[i][j], 0, 0, 0);
                    }
            }
            __builtin_amdgcn_s_setprio(0);
            __syncthreads();
            cur ^= 1;
        }

        // ----- per-plane epilogue -----
        if (p == 2) {                            // zero cnt before accumulation
            for (int w = tid; w < 1024; w += 512) cnt[w] = 0;
            __syncthreads();
        }

#pragma unroll
        for (int j = 0; j < 2; ++j) {
            const int dl = dw + j * 32 + row32;  // [0,128)
            const int d  = d0g + dl;
            const float sc = scale[d], sh = shift[d];
            const int c = dl0 + dl;              // channel [0,512)
            const int dlblk = (dw >> 5) + j;     // [0,4)
            int rsum[4][2] = {{0,0},{0,0},{0,0},{0,0}};
#pragma unroll
            for (int i = 0; i < 2; ++i) {
                const int bnb = (m0 + mw + i * 32) >> 2;
                f32x16 a = acc[i][j];
#pragma unroll
                for (int g4 = 0; g4 < 4; ++g4) {
                    int bn = bnb + 2 * g4 + khalf;
                    float p0 = fmaf(a[4 * g4 + 0], sc, sh);
                    float p1 = fmaf(a[4 * g4 + 1], sc, sh);
                    float p2 = fmaf(a[4 * g4 + 2], sc, sh);
                    float p3 = fmaf(a[4 * g4 + 3], sc, sh);
                    float vm = p0 * 0.5f;
                    bool s0 = (vm >= 1.f); if (s0) vm = 0.f;
                    vm = vm + (p1 - vm) * 0.5f;
                    bool s1 = (vm >= 1.f); if (s1) vm = 0.f;
                    vm = vm + (p2 - vm) * 0.5f;
                    bool s2 = (vm >= 1.f); if (s2) vm = 0.f;
                    vm = vm + (p3 - vm) * 0.5f;
                    bool s3 = (vm >= 1.f);

                    if (p == 0) {
                        // q spikes: linear [t][b][n][c] planes (out_gemm input)
                        ushort_t* bp = qspk + (size_t)bn * 512 + c;
                        bp[0]                      = s0 ? 0x3F80 : 0;
                        bp[(size_t)BNP_ * 512]     = s1 ? 0x3F80 : 0;
                        bp[(size_t)2 * BNP_ * 512] = s2 ? 0x3F80 : 0;
                        bp[(size_t)3 * BNP_ * 512] = s3 ? 0x3F80 : 0;
                    } else if (p == 1) {
                        // k spikes -> LDS bitmask (1 ballot fills 2 bn rows)
                        const int bnl_e = (bnb + 2 * g4) - bn0;      // even row
                        const int widx = bnl_e * 16 + 0 * 4 + dlblk; // t added below
                        bool sarr[4] = {s0, s1, s2, s3};
#pragma unroll
                        for (int t = 0; t < 4; ++t) {
                            unsigned long long bm = __ballot(sarr[t]);
                            if (lane == 0)
                                kmask[widx + t * 4]      = (unsigned)bm;
                            else if (lane == 32)
                                kmask[widx + t * 4 + 16] = (unsigned)(bm >> 32);
                        }
                    } else {
                        // v: out2 (vh) write + AND with k-bit -> rsum
                        int b = bn / N_, n = bn - b * N_;
                        float* o = out2 + (((size_t)b * 8 + (c >> 6)) * N_ + n) * 64 + (c & 63);
                        o[0]                       = s0 ? 1.f : 0.f;
                        o[(size_t)1 * (OUT1_ / 4)] = s1 ? 1.f : 0.f;
                        o[(size_t)2 * (OUT1_ / 4)] = s2 ? 1.f : 0.f;
                        o[(size_t)3 * (OUT1_ / 4)] = s3 ? 1.f : 0.f;
                        const int bnl = bn - bn0;
                        const int slot = (bnl >= bsplit) ? 1 : 0;
                        bool sarr[4] = {s0, s1, s2, s3};
#pragma unroll
                        for (int t = 0; t < 4; ++t) {
                            unsigned kw_ = kmask[bnl * 16 + t * 4 + dlblk];
                            rsum[t][slot] += (int)((kw_ >> row32) & 1u) & (sarr[t] ? 1 : 0);
                        }
                    }
                }
            }
            if (p == 2) {
#pragma unroll
                for (int t = 0; t < 4; ++t) {
                    if (rsum[t][0]) atomicAdd(&cnt[t * 256 + 0 + dl], rsum[t][0]);
                    if (rsum[t][1]) atomicAdd(&cnt[t * 256 + 128 + dl], rsum[t][1]);
                }
            }
        }

        if (p == 2) {
            __syncthreads();
            for (int w = tid; w < 1024; w += 512) {
                int val = cnt[w];
                if (val) {
                    int t = w >> 8, slot = (w >> 7) & 1, dl = w & 127;
                    int b = b0 + slot;
                    atomicAdd(&kvpart[(t * 32 + b) * 512 + dl0 + dl], (float)val);
                }
            }
        }
        __syncthreads();   // all waves done with dbufs/kmask before next plane
    }
}

// ---------------------------------------------------------------------------
// K4: LIF over t on kvpart -> kv spikes bf16 [tb][c]
// ---------------------------------------------------------------------------
__global__ void kv_lif_kernel(const float* __restrict__ kvpart, ushort_t* __restrict__ kvs)
{
    int i = blockIdx.x * 256 + threadIdx.x;      // 32*512
    if (i >= B_ * C_) return;
    int b = i >> 9, c = i & 511;
    float v = 0.f;
#pragma unroll
    for (int t = 0; t < T_; ++t) {
        float y = kvpart[((t * B_ + b) << 9) + c];
        v = v + (y - v) * 0.5f;
        bool s = (v >= 1.f);
        kvs[((t * B_ + b) << 9) + c] = s ? 0x3F80 : 0;
        if (s) v = 0.f;
    }
}

// ---------------------------------------------------------------------------
// K6: out GEMM with fused muly (unchanged from round 7 — passed).
// ---------------------------------------------------------------------------
__global__ __launch_bounds__(256)
void out_gemm(const ushort_t* __restrict__ A, const ushort_t* __restrict__ qs,
              const ushort_t* __restrict__ kvs,
              const float* __restrict__ scale, const float* __restrict__ shift,
              const float* __restrict__ xid, float* __restrict__ out)
{
    const int id = blockIdx.x;
    const int xw = id & 7, local = id >> 3;      // local < 100
    const int m_t = (local >> 2) * 8 + xw, d_t = local & 3;
    if (m_t >= 196) return;
    const int m0 = m_t * 128, d0 = d_t * 128;

    __shared__ ushort_t As[2][8 * 512];  // dbuf x [db(4)][ks(2)]
    __shared__ ushort_t Bs[2][8 * 512];  // dbuf x [mb(4)][ks(2)]
    const int tid = threadIdx.x, wid = tid >> 6, lane = tid & 63;
    const int dw = (wid >> 1) * 64, mw = (wid & 1) * 64;
    const int row32 = lane & 31, khalf = lane >> 5;

    int sm[2], stb[2], sq[2], sL[2];
#pragma unroll
    for (int u = 0; u < 2; ++u) {
        int s = tid + u * 256;
        sq[u] = s >> 6; sL[u] = s & 63;
        sm[u] = m0 + (sq[u] >> 1) * 32 + (sL[u] & 31);
        stb[u] = sm[u] / N_;
    }

    f32x16 acc[2][2] = {};               // [i: d-block32][j: m-block32]

    {
        uint4 o[2];
#pragma unroll
        for (int u = 0; u < 2; ++u) {
            int kk = (sq[u] & 1) * 16 + (sL[u] >> 5) * 8;
            uint4 qv = *reinterpret_cast<const uint4*>(&qs[(size_t)sm[u] * 512 + kk]);
            uint4 kv = *reinterpret_cast<const uint4*>(&kvs[(size_t)stb[u] * 512 + kk]);
            o[u].x = qv.x & kv.x; o[u].y = qv.y & kv.y;
            o[u].z = qv.z & kv.z; o[u].w = qv.w & kv.w;
        }
        for (int q = wid; q < 8; q += 4) {
            int db = q >> 1, ks2 = q & 1;
            const ushort_t* g = A + (size_t)(d0 + db * 32 + row32) * 512 + ks2 * 16 + khalf * 8;
            GL2LDS(g, &As[0][q * 512]);
        }
#pragma unroll
        for (int u = 0; u < 2; ++u)
            *reinterpret_cast<uint4*>(&Bs[0][sq[u] * 512 + sL[u] * 8]) = o[u];
    }
    __syncthreads();

    int buf = 0;
    for (int it = 0; it < 16; ++it) {
        uint4 nq[2], nk[2];
        if (it < 15) {
            int k0n = (it + 1) * 32;
#pragma unroll
            for (int u = 0; u < 2; ++u) {
                int kk = k0n + (sq[u] & 1) * 16 + (sL[u] >> 5) * 8;
                nq[u] = *reinterpret_cast<const uint4*>(&qs[(size_t)sm[u] * 512 + kk]);
                nk[u] = *reinterpret_cast<const uint4*>(&kvs[(size_t)stb[u] * 512 + kk]);
            }
            for (int q = wid; q < 8; q += 4) {
                int db = q >> 1, ks2 = q & 1;
                const ushort_t* g = A + (size_t)(d0 + db * 32 + row32) * 512 + k0n + ks2 * 16 + khalf * 8;
                GL2LDS(g, &As[buf ^ 1][q * 512]);
            }
        }

        __builtin_amdgcn_s_setprio(1);
#pragma unroll
        for (int ks = 0; ks < 2; ++ks) {
            bf16x8 afr[2];
#pragma unroll
            for (int i = 0; i < 2; ++i)
                afr[i] = *reinterpret_cast<const bf16x8*>(
                    &As[buf][(((dw >> 5) + i) * 2 + ks) * 512 + lane * 8]);
#pragma unroll
            for (int j = 0; j < 2; ++j) {
                bf16x8 bfr = *reinterpret_cast<const bf16x8*>(
                    &Bs[buf][(((mw >> 5) + j) * 2 + ks) * 512 + lane * 8]);
#pragma unroll
                for (int i = 0; i < 2; ++i)
                    acc[i][j] = __builtin_amdgcn_mfma_f32_32x32x16_bf16(afr[i], bfr, acc[i][j], 0, 0, 0);
            }
        }
        __builtin_amdgcn_s_setprio(0);

        if (it < 15) {
#pragma unroll
            for (int u = 0; u < 2; ++u) {
                uint4 o;
                o.x = nq[u].x & nk[u].x; o.y = nq[u].y & nk[u].y;
                o.z = nq[u].z & nk[u].z; o.w = nq[u].w & nk[u].w;
                *reinterpret_cast<uint4*>(&Bs[buf ^ 1][sq[u] * 512 + sL[u] * 8]) = o;
            }
        }
        __syncthreads();
        buf ^= 1;
    }

#pragma unroll
    for (int j = 0; j < 2; ++j) {
        int m = m0 + mw + j * 32 + row32;
        int tb = m / N_;
        int n  = m - tb * N_;
        size_t mbase = (size_t)tb * (C_ * N_) + n;
#pragma unroll
        for (int i = 0; i < 2; ++i) {
            int dbase = d0 + dw + i * 32 + 4 * khalf;
            f32x16 a = acc[i][j];
#pragma unroll
            for (int g = 0; g < 4; ++g) {
#pragma unroll
                for (int t = 0; t < 4; ++t) {
                    int d = dbase + t + 8 * g;
                    float val = fmaf(a[4 * g + t], scale[d], shift[d]);
                    size_t ad = mbase + (size_t)d * N_;
                    out[ad] = val + xid[ad];
                }
            }
        }
    }
}

// ---------------------------------------------------------------------------
extern "C" void kernel_launch(void* const* d_in, const int* in_sizes, int n_in,
                              void* d_out, int out_size, void* d_ws, size_t ws_size,
                              hipStream_t stream)
{
    const float* x    = (const float*)d_in[0];
    const float* q_w  = (const float*)d_in[1];
    const float* k_w  = (const float*)d_in[2];
    const float* v_w  = (const float*)d_in[3];
    const float* o_w  = (const float*)d_in[4];
    const float* o_b  = (const float*)d_in[5];
    const float* qg = (const float*)d_in[6],  *qb = (const float*)d_in[7],
               *qm = (const float*)d_in[8],  *qv = (const float*)d_in[9];
    const float* kg = (const float*)d_in[10], *kb = (const float*)d_in[11],
               *km = (const float*)d_in[12], *kv = (const float*)d_in[13];
    const float* vg = (const float*)d_in[14], *vb = (const float*)d_in[15],
               *vm = (const float*)d_in[16], *vv = (const float*)d_in[17];
    const float* og = (const float*)d_in[18], *ob = (const float*)d_in[19],
               *om = (const float*)d_in[20], *ov = (const float*)d_in[21];

    float* out1  = (float*)d_out;
    float* out2f = out1 + OUT1_;

    // d_ws layout (unchanged; k/v spike planes now unused but reserved)
    ushort_t* spk    = (ushort_t*)d_ws;                      // [3][M][512] bf16 spikes
    ushort_t* xs     = spk + (size_t)3 * M_ * 512;           // [M][512] bf16 (m' order)
    ushort_t* wsplit = xs + (size_t)M_ * 512;                // 1536*2*512
    ushort_t* osplit = wsplit + (size_t)1536 * 2 * 512;      // 512*512
    float*    kvpart = (float*)(osplit + (size_t)512 * 512); // [TB][C]
    ushort_t* kvs    = (ushort_t*)(kvpart + TB_ * C_);       // [TB][C]
    float*    scq    = (float*)(kvs + TB_ * C_);
    float*    shq    = scq + 3 * C_;
    float*    sco    = shq + 3 * C_;
    float*    sho    = sco + C_;

    ushort_t* qsp = spk;

    prep_lifx_kernel<<<4096, 256, 0, stream>>>(
        q_w, k_w, v_w, o_w,
        qg, qb, qm, qv, kg, kb, km, kv, vg, vb, vm, vv, og, ob, om, ov, o_b,
        wsplit, osplit, scq, shq, sco, sho, kvpart, x, xs);

    qkv_gemm_lif<<<392, 512, 0, stream>>>(wsplit, xs, scq, shq, qsp, out2f, kvpart);

    kv_lif_kernel<<<64, 256, 0, stream>>>(kvpart, kvs);

    out_gemm<<<800, 256, 0, stream>>>(osplit, qsp, kvs, sco, sho, x, out1);
}

// Round 9
// 476.866 us; speedup vs baseline: 1.3151x; 1.3151x over previous
//
#include <hip/hip_runtime.h>
#include <math.h>

#define T_   4
#define B_   32
#define C_   512
#define N_   196
#define TB_  128
#define M_   25088          // TB_*N_
#define BNP_ 6272           // B_*N_  (t-plane stride in bn-space)
#define OUT1_ 12845056      // T_*B_*C_*N_

typedef unsigned short ushort_t;
typedef __attribute__((ext_vector_type(8)))  __bf16 bf16x8;
typedef __attribute__((ext_vector_type(16))) float  f32x16;

__device__ __forceinline__ ushort_t f2bf(float f) {
    unsigned int u = __float_as_uint(f);
    u = u + 0x7FFFu + ((u >> 16) & 1u);      // RN-even
    return (ushort_t)(u >> 16);
}
__device__ __forceinline__ float bf2f(ushort_t h) {
    return __uint_as_float(((unsigned int)h) << 16);
}

#define GL2LDS(gp, lp) \
    __builtin_amdgcn_global_load_lds((const __attribute__((address_space(1))) void*)(gp), \
                                     (__attribute__((address_space(3))) void*)(lp), 16, 0, 0)

// ---------------------------------------------------------------------------
// K0+K1 merged: blocks [0,3072) = prep; blocks [3072,4096) = lifx.
// (unchanged from round 7 — passed)
// ---------------------------------------------------------------------------
__global__ __launch_bounds__(256)
void prep_lifx_kernel(
    const float* __restrict__ qw, const float* __restrict__ kw,
    const float* __restrict__ vw, const float* __restrict__ ow,
    const float* __restrict__ qg, const float* __restrict__ qb, const float* __restrict__ qm, const float* __restrict__ qv,
    const float* __restrict__ kg, const float* __restrict__ kb, const float* __restrict__ km, const float* __restrict__ kvr,
    const float* __restrict__ vg, const float* __restrict__ vb, const float* __restrict__ vm, const float* __restrict__ vv,
    const float* __restrict__ og, const float* __restrict__ ob, const float* __restrict__ om, const float* __restrict__ ov,
    const float* __restrict__ obias,
    ushort_t* __restrict__ wsplit, ushort_t* __restrict__ osplit,
    float* __restrict__ scale_qkv, float* __restrict__ shift_qkv,
    float* __restrict__ scale_o,   float* __restrict__ shift_o,
    float* __restrict__ kvpart,
    const float* __restrict__ x, ushort_t* __restrict__ xs)
{
    __shared__ ushort_t tile[64 * 66];
    const int bid = blockIdx.x;
    const int tid = threadIdx.x;

    if (bid < 3072) {
        int i = bid * 256 + tid;                 // [0, 1536*512)
        int d = i >> 9, c = i & 511;
        const float* src = (d < 512) ? qw : (d < 1024) ? kw : vw;
        float wv = src[(d & 511) * 512 + c];
        ushort_t h = f2bf(wv);
        float r1 = wv - bf2f(h);
        ushort_t mm = f2bf(r1);
        wsplit[((size_t)d * 2 + 0) * 512 + c] = h;
        wsplit[((size_t)d * 2 + 1) * 512 + c] = mm;
        if (d < 512)
            osplit[(size_t)d * 512 + c] = f2bf(ow[d * 512 + c]);

        if (i < 3 * C_) {
            int p = i >> 9, dl = i & 511;
            const float* g = (p == 0) ? qg : (p == 1) ? kg : vg;
            const float* b = (p == 0) ? qb : (p == 1) ? kb : vb;
            const float* m = (p == 0) ? qm : (p == 1) ? km : vm;
            const float* r = (p == 0) ? qv : (p == 1) ? kvr : vv;
            float sc = g[dl] / sqrtf(r[dl] + 1e-5f);
            scale_qkv[i] = sc;
            shift_qkv[i] = b[dl] - m[dl] * sc;
        }
        if (i < C_) {
            float sc = og[i] / sqrtf(ov[i] + 1e-5f);
            scale_o[i] = sc;
            shift_o[i] = ob[i] - om[i] * sc + obias[i] * sc;
        }
        if (i < TB_ * C_) kvpart[i] = 0.f;
        return;
    }

    const int l = bid - 3072;                    // [0, 1024)
    const int n0 = (l & 3) * 64;
    const int c0 = ((l >> 2) & 7) * 64;
    const int b  = l >> 5;
    const int j = tid & 63, w = tid >> 6;
    const bool nok = (n0 + j) < N_;
    float v[16];
#pragma unroll
    for (int r = 0; r < 16; ++r) v[r] = 0.f;
    for (int t = 0; t < T_; ++t) {
        const float* xb = x + ((size_t)((t * B_ + b) * C_ + c0)) * N_ + n0 + j;
#pragma unroll
        for (int r = 0; r < 16; ++r) {
            int i = w * 16 + r;
            float xv = nok ? xb[(size_t)i * N_] : 0.f;
            v[r] = v[r] + (xv - v[r]) * 0.5f;
            bool s = (v[r] >= 1.0f);
            tile[j * 66 + i] = s ? 0x3F80 : 0;
            if (s) v[r] = 0.f;
        }
        __syncthreads();
#pragma unroll
        for (int p = 0; p < 2; ++p) {
            int w2 = tid + p * 256;
            int jj = w2 >> 3, ck = w2 & 7;
            if (n0 + jj < N_) {
                const unsigned int* src = reinterpret_cast<const unsigned int*>(&tile[jj * 66 + ck * 8]);
                uint4 dv; dv.x = src[0]; dv.y = src[1]; dv.z = src[2]; dv.w = src[3];
                size_t mp = (size_t)(b * N_ + n0 + jj) * 4 + t;      // permuted row
                *reinterpret_cast<uint4*>(&xs[mp * 512 + c0 + ck * 8]) = dv;
            }
        }
        __syncthreads();
    }
}

// ---------------------------------------------------------------------------
// K2: qkv GEMM — round-7 structure verbatim (1200 blocks, m-major XCD
// swizzle, 2-phase dbuf K-loop, 512 thr). ONE change (round 9): k and v
// plane blocks no longer write bf16 spike planes (51.4 MB); they emit
// 1-bit spike bitmasks via __ballot (logic numerically proven in round 8):
//   word (t, bn, cw) = spikes of 32 consecutive channels; low 32 lanes
//   (khalf=0, bn even) -> lane 0 writes low word, high 32 lanes (khalf=1,
//   bn odd) -> lane 32 writes high word. 1.6 MB per plane. q plane and
//   out2 (vh) writes unchanged. No word is written twice (bn set is
//   disjoint across mw; cw disjoint across dw/j/d_t).
// ---------------------------------------------------------------------------
__global__ __launch_bounds__(512, 4)
void qkv_gemm_lif(const ushort_t* __restrict__ W, const ushort_t* __restrict__ X,
                  const float* __restrict__ scale, const float* __restrict__ shift,
                  ushort_t* __restrict__ qspk, float* __restrict__ out2,
                  unsigned* __restrict__ kbit, unsigned* __restrict__ vbit)
{
    const int id = blockIdx.x;
    const int xw = id & 7, local = id >> 3;      // local in [0,150)
    const int ml = local / 12, d_t = local - ml * 12;
    const int m_t = ml * 8 + xw;
    if (m_t >= 98) return;
    const int m0 = m_t * 256;                    // m' base (256-tile)
    const int d0 = d_t * 128;                    // global d in [0,1536)

    __shared__ ushort_t Xs[2][16 * 512];  // dbuf x 16 chunks of 1KB: [mb(8)][ks(2)]
    __shared__ ushort_t Ws[2][16 * 512];  // dbuf x 16 chunks: [s(2)][db(4)][ks(2)]
    const int tid = threadIdx.x, wid = tid >> 6, lane = tid & 63;
    const int mw = (wid & 3) * 64, dw = (wid >> 2) * 64;
    const int row32 = lane & 31, khalf = lane >> 5;

    f32x16 acc[2][2] = {};               // [i: m-block32][j: d-block32]

    auto STAGE = [&](int buf, int k0) {
        {   int q = wid, mb = q >> 1, ks = q & 1;
            const ushort_t* g = X + (size_t)(m0 + mb * 32 + row32) * 512 + k0 + ks * 16 + khalf * 8;
            GL2LDS(g, &Xs[buf][q * 512]);
        }
        {   int q = wid + 8, mb = q >> 1, ks = q & 1;
            const ushort_t* g = X + (size_t)(m0 + mb * 32 + row32) * 512 + k0 + ks * 16 + khalf * 8;
            GL2LDS(g, &Xs[buf][q * 512]);
        }
        {   int q = wid, s = q >> 3, rem = q & 7, db = rem >> 1, ks = rem & 1;
            const ushort_t* g = W + ((size_t)(d0 + db * 32 + row32) * 2 + s) * 512 + k0 + ks * 16 + khalf * 8;
            GL2LDS(g, &Ws[buf][q * 512]);
        }
        {   int q = wid + 8, s = q >> 3, rem = q & 7, db = rem >> 1, ks = rem & 1;
            const ushort_t* g = W + ((size_t)(d0 + db * 32 + row32) * 2 + s) * 512 + k0 + ks * 16 + khalf * 8;
            GL2LDS(g, &Ws[buf][q * 512]);
        }
    };

    STAGE(0, 0);
    __syncthreads();
    int cur = 0;

    for (int it = 0; it < 16; ++it) {
        if (it < 15) STAGE(cur ^ 1, (it + 1) * 32);

        __builtin_amdgcn_s_setprio(1);
#pragma unroll
        for (int ks = 0; ks < 2; ++ks) {
            bf16x8 xfr[2];
#pragma unroll
            for (int i = 0; i < 2; ++i)
                xfr[i] = *reinterpret_cast<const bf16x8*>(
                    &Xs[cur][(((mw >> 5) + i) * 2 + ks) * 512 + lane * 8]);
#pragma unroll
            for (int s = 0; s < 2; ++s)
#pragma unroll
                for (int j = 0; j < 2; ++j) {
                    bf16x8 wfr = *reinterpret_cast<const bf16x8*>(
                        &Ws[cur][(s * 8 + ((dw >> 5) + j) * 2 + ks) * 512 + lane * 8]);
#pragma unroll
                    for (int i = 0; i < 2; ++i)
                        acc[i][j] = __builtin_amdgcn_mfma_f32_32x32x16_bf16(xfr[i], wfr, acc[i][j], 0, 0, 0);
                }
        }
        __builtin_amdgcn_s_setprio(0);
        __syncthreads();
        cur ^= 1;
    }

    // epilogue: BN -> LIF over t (reg&3).
    // q plane: bf16 spikes [t][bn][c] (out_gemm input). k/v: bitmask words.
    // v additionally writes out2[t][b][h][n][hd] fp32.
    const int p = d0 >> 9;
    const bool isQ = (p == 0), isV = (p == 2);
    unsigned* __restrict__ bitp = (p == 1) ? kbit : vbit;
#pragma unroll
    for (int j = 0; j < 2; ++j) {
        int d = d0 + dw + j * 32 + row32;
        float sc = scale[d], sh = shift[d];
        int dl = d & 511;
        int h = dl >> 6, hd = dl & 63;
        int cw = ((d0 & 511) + dw + j * 32) >> 5;    // uniform per wave: [0,16)
#pragma unroll
        for (int i = 0; i < 2; ++i) {
            int bnb = (m0 + mw + i * 32) >> 2;
            f32x16 a = acc[i][j];
#pragma unroll
            for (int g = 0; g < 4; ++g) {
                int bn = bnb + 2 * g + khalf;
                float p0 = fmaf(a[4 * g + 0], sc, sh);
                float p1 = fmaf(a[4 * g + 1], sc, sh);
                float p2 = fmaf(a[4 * g + 2], sc, sh);
                float p3 = fmaf(a[4 * g + 3], sc, sh);
                float v = p0 * 0.5f;
                bool s0 = (v >= 1.f); if (s0) v = 0.f;
                v = v + (p1 - v) * 0.5f;
                bool s1 = (v >= 1.f); if (s1) v = 0.f;
                v = v + (p2 - v) * 0.5f;
                bool s2 = (v >= 1.f); if (s2) v = 0.f;
                v = v + (p3 - v) * 0.5f;
                bool s3 = (v >= 1.f);

                if (isQ) {
                    ushort_t* b0 = qspk + (size_t)bn * 512 + dl;
                    b0[0]                      = s0 ? 0x3F80 : 0;
                    b0[(size_t)BNP_ * 512]     = s1 ? 0x3F80 : 0;
                    b0[(size_t)2 * BNP_ * 512] = s2 ? 0x3F80 : 0;
                    b0[(size_t)3 * BNP_ * 512] = s3 ? 0x3F80 : 0;
                } else {
                    // bitmask: one ballot fills both bn rows (even via lane 0,
                    // odd via lane 32). Proven correct in round 8.
                    const int bn_e = bnb + 2 * g;
                    bool sarr[4] = {s0, s1, s2, s3};
#pragma unroll
                    for (int t = 0; t < 4; ++t) {
                        unsigned long long bm = __ballot(sarr[t]);
                        if (lane == 0)
                            bitp[((size_t)t * BNP_ + bn_e) * 16 + cw] = (unsigned)bm;
                        else if (lane == 32)
                            bitp[((size_t)t * BNP_ + bn_e + 1) * 16 + cw] = (unsigned)(bm >> 32);
                    }
                    if (isV) {
                        int b = bn / N_, n = bn - b * N_;
                        float* o = out2 + (((size_t)b * 8 + h) * N_ + n) * 64 + hd;
                        o[0]                       = s0 ? 1.f : 0.f;
                        o[(size_t)1 * (OUT1_ / 4)] = s1 ? 1.f : 0.f;
                        o[(size_t)2 * (OUT1_ / 4)] = s2 ? 1.f : 0.f;
                        o[(size_t)3 * (OUT1_ / 4)] = s3 ? 1.f : 0.f;
                    }
                }
            }
        }
    }
}

// ---------------------------------------------------------------------------
// K3 (round 9): fused kv-reduce + LIF from bitmasks. Thread owns (b,c):
// for each t, cnt = sum_n (kbit & vbit) bit c over n; LIF over t in-register;
// write kvs. Word loads are uniform across each 32-lane group (broadcast).
// Replaces kv_part (51 MB reads) + kv_lif + one launch. Exact int counts.
// ---------------------------------------------------------------------------
__global__ __launch_bounds__(256)
void kv_bit_lif(const unsigned* __restrict__ kbit, const unsigned* __restrict__ vbit,
                ushort_t* __restrict__ kvs)
{
    int id = blockIdx.x * 256 + threadIdx.x;     // 32*512 = 16384
    if (id >= B_ * C_) return;
    int b = id >> 9, c = id & 511;
    int cw = c >> 5, bit = c & 31;
    float v = 0.f;
#pragma unroll
    for (int t = 0; t < T_; ++t) {
        size_t base = ((size_t)t * BNP_ + (size_t)b * N_) * 16 + cw;
        int cnt = 0;
        for (int n = 0; n < N_; ++n) {
            unsigned kw = kbit[base + (size_t)n * 16];
            unsigned vw = vbit[base + (size_t)n * 16];
            cnt += (int)(((kw & vw) >> bit) & 1u);
        }
        float y = (float)cnt;
        v = v + (y - v) * 0.5f;
        bool s = (v >= 1.f);
        kvs[((t * B_ + b) << 9) + c] = s ? 0x3F80 : 0;
        if (s) v = 0.f;
    }
}

// ---------------------------------------------------------------------------
// K6: out GEMM with fused muly (unchanged from round 7 — passed).
// ---------------------------------------------------------------------------
__global__ __launch_bounds__(256)
void out_gemm(const ushort_t* __restrict__ A, const ushort_t* __restrict__ qs,
              const ushort_t* __restrict__ kvs,
              const float* __restrict__ scale, const float* __restrict__ shift,
              const float* __restrict__ xid, float* __restrict__ out)
{
    const int id = blockIdx.x;
    const int xw = id & 7, local = id >> 3;      // local < 100
    const int m_t = (local >> 2) * 8 + xw, d_t = local & 3;
    if (m_t >= 196) return;
    const int m0 = m_t * 128, d0 = d_t * 128;

    __shared__ ushort_t As[2][8 * 512];  // dbuf x [db(4)][ks(2)]
    __shared__ ushort_t Bs[2][8 * 512];  // dbuf x [mb(4)][ks(2)]
    const int tid = threadIdx.x, wid = tid >> 6, lane = tid & 63;
    const int dw = (wid >> 1) * 64, mw = (wid & 1) * 64;
    const int row32 = lane & 31, khalf = lane >> 5;

    int sm[2], stb[2], sq[2], sL[2];
#pragma unroll
    for (int u = 0; u < 2; ++u) {
        int s = tid + u * 256;
        sq[u] = s >> 6; sL[u] = s & 63;
        sm[u] = m0 + (sq[u] >> 1) * 32 + (sL[u] & 31);
        stb[u] = sm[u] / N_;
    }

    f32x16 acc[2][2] = {};               // [i: d-block32][j: m-block32]

    {
        uint4 o[2];
#pragma unroll
        for (int u = 0; u < 2; ++u) {
            int kk = (sq[u] & 1) * 16 + (sL[u] >> 5) * 8;
            uint4 qv = *reinterpret_cast<const uint4*>(&qs[(size_t)sm[u] * 512 + kk]);
            uint4 kv = *reinterpret_cast<const uint4*>(&kvs[(size_t)stb[u] * 512 + kk]);
            o[u].x = qv.x & kv.x; o[u].y = qv.y & kv.y;
            o[u].z = qv.z & kv.z; o[u].w = qv.w & kv.w;
        }
        for (int q = wid; q < 8; q += 4) {
            int db = q >> 1, ks2 = q & 1;
            const ushort_t* g = A + (size_t)(d0 + db * 32 + row32) * 512 + ks2 * 16 + khalf * 8;
            GL2LDS(g, &As[0][q * 512]);
        }
#pragma unroll
        for (int u = 0; u < 2; ++u)
            *reinterpret_cast<uint4*>(&Bs[0][sq[u] * 512 + sL[u] * 8]) = o[u];
    }
    __syncthreads();

    int buf = 0;
    for (int it = 0; it < 16; ++it) {
        uint4 nq[2], nk[2];
        if (it < 15) {
            int k0n = (it + 1) * 32;
#pragma unroll
            for (int u = 0; u < 2; ++u) {
                int kk = k0n + (sq[u] & 1) * 16 + (sL[u] >> 5) * 8;
                nq[u] = *reinterpret_cast<const uint4*>(&qs[(size_t)sm[u] * 512 + kk]);
                nk[u] = *reinterpret_cast<const uint4*>(&kvs[(size_t)stb[u] * 512 + kk]);
            }
            for (int q = wid; q < 8; q += 4) {
                int db = q >> 1, ks2 = q & 1;
                const ushort_t* g = A + (size_t)(d0 + db * 32 + row32) * 512 + k0n + ks2 * 16 + khalf * 8;
                GL2LDS(g, &As[buf ^ 1][q * 512]);
            }
        }

        __builtin_amdgcn_s_setprio(1);
#pragma unroll
        for (int ks = 0; ks < 2; ++ks) {
            bf16x8 afr[2];
#pragma unroll
            for (int i = 0; i < 2; ++i)
                afr[i] = *reinterpret_cast<const bf16x8*>(
                    &As[buf][(((dw >> 5) + i) * 2 + ks) * 512 + lane * 8]);
#pragma unroll
            for (int j = 0; j < 2; ++j) {
                bf16x8 bfr = *reinterpret_cast<const bf16x8*>(
                    &Bs[buf][(((mw >> 5) + j) * 2 + ks) * 512 + lane * 8]);
#pragma unroll
                for (int i = 0; i < 2; ++i)
                    acc[i][j] = __builtin_amdgcn_mfma_f32_32x32x16_bf16(afr[i], bfr, acc[i][j], 0, 0, 0);
            }
        }
        __builtin_amdgcn_s_setprio(0);

        if (it < 15) {
#pragma unroll
            for (int u = 0; u < 2; ++u) {
                uint4 o;
                o.x = nq[u].x & nk[u].x; o.y = nq[u].y & nk[u].y;
                o.z = nq[u].z & nk[u].z; o.w = nq[u].w & nk[u].w;
                *reinterpret_cast<uint4*>(&Bs[buf ^ 1][sq[u] * 512 + sL[u] * 8]) = o;
            }
        }
        __syncthreads();
        buf ^= 1;
    }

#pragma unroll
    for (int j = 0; j < 2; ++j) {
        int m = m0 + mw + j * 32 + row32;
        int tb = m / N_;
        int n  = m - tb * N_;
        size_t mbase = (size_t)tb * (C_ * N_) + n;
#pragma unroll
        for (int i = 0; i < 2; ++i) {
            int dbase = d0 + dw + i * 32 + 4 * khalf;
            f32x16 a = acc[i][j];
#pragma unroll
            for (int g = 0; g < 4; ++g) {
#pragma unroll
                for (int t = 0; t < 4; ++t) {
                    int d = dbase + t + 8 * g;
                    float val = fmaf(a[4 * g + t], scale[d], shift[d]);
                    size_t ad = mbase + (size_t)d * N_;
                    out[ad] = val + xid[ad];
                }
            }
        }
    }
}

// ---------------------------------------------------------------------------
extern "C" void kernel_launch(void* const* d_in, const int* in_sizes, int n_in,
                              void* d_out, int out_size, void* d_ws, size_t ws_size,
                              hipStream_t stream)
{
    const float* x    = (const float*)d_in[0];
    const float* q_w  = (const float*)d_in[1];
    const float* k_w  = (const float*)d_in[2];
    const float* v_w  = (const float*)d_in[3];
    const float* o_w  = (const float*)d_in[4];
    const float* o_b  = (const float*)d_in[5];
    const float* qg = (const float*)d_in[6],  *qb = (const float*)d_in[7],
               *qm = (const float*)d_in[8],  *qv = (const float*)d_in[9];
    const float* kg = (const float*)d_in[10], *kb = (const float*)d_in[11],
               *km = (const float*)d_in[12], *kv = (const float*)d_in[13];
    const float* vg = (const float*)d_in[14], *vb = (const float*)d_in[15],
               *vm = (const float*)d_in[16], *vv = (const float*)d_in[17];
    const float* og = (const float*)d_in[18], *ob = (const float*)d_in[19],
               *om = (const float*)d_in[20], *ov = (const float*)d_in[21];

    float* out1  = (float*)d_out;
    float* out2f = out1 + OUT1_;

    // d_ws layout (k/v plane regions reused for bitmasks, 1.6 MB each)
    ushort_t* spk    = (ushort_t*)d_ws;                      // q: [M][512] bf16 spikes
    ushort_t* xs     = spk + (size_t)3 * M_ * 512;           // [M][512] bf16 (m' order)
    ushort_t* wsplit = xs + (size_t)M_ * 512;                // 1536*2*512
    ushort_t* osplit = wsplit + (size_t)1536 * 2 * 512;      // 512*512
    float*    kvpart = (float*)(osplit + (size_t)512 * 512); // [TB][C] (vestigial)
    ushort_t* kvs    = (ushort_t*)(kvpart + TB_ * C_);       // [TB][C]
    float*    scq    = (float*)(kvs + TB_ * C_);
    float*    shq    = scq + 3 * C_;
    float*    sco    = shq + 3 * C_;
    float*    sho    = sco + C_;

    ushort_t* qsp = spk;
    unsigned* kbit = (unsigned*)(spk + (size_t)M_ * 512);        // in old k-plane
    unsigned* vbit = (unsigned*)(spk + (size_t)2 * M_ * 512);    // in old v-plane

    prep_lifx_kernel<<<4096, 256, 0, stream>>>(
        q_w, k_w, v_w, o_w,
        qg, qb, qm, qv, kg, kb, km, kv, vg, vb, vm, vv, og, ob, om, ov, o_b,
        wsplit, osplit, scq, shq, sco, sho, kvpart, x, xs);

    qkv_gemm_lif<<<1200, 512, 0, stream>>>(wsplit, xs, scq, shq, qsp, out2f, kbit, vbit);

    kv_bit_lif<<<64, 256, 0, stream>>>(kbit, vbit, kvs);

    out_gemm<<<800, 256, 0, stream>>>(osplit, qsp, kvs, sco, sho, x, out1);
}

// Round 11
// 400.662 us; speedup vs baseline: 1.5652x; 1.1902x over previous
//
#include <hip/hip_runtime.h>
#include <math.h>

#define T_   4
#define B_   32
#define C_   512
#define N_   196
#define TB_  128
#define M_   25088          // TB_*N_
#define BNP_ 6272           // B_*N_  (t-plane stride in bn-space)
#define OUT1_ 12845056      // T_*B_*C_*N_

typedef unsigned short ushort_t;
typedef __attribute__((ext_vector_type(8)))  __bf16 bf16x8;
typedef __attribute__((ext_vector_type(16))) float  f32x16;

__device__ __forceinline__ ushort_t f2bf(float f) {
    unsigned int u = __float_as_uint(f);
    u = u + 0x7FFFu + ((u >> 16) & 1u);      // RN-even
    return (ushort_t)(u >> 16);
}
__device__ __forceinline__ float bf2f(ushort_t h) {
    return __uint_as_float(((unsigned int)h) << 16);
}

#define GL2LDS(gp, lp) \
    __builtin_amdgcn_global_load_lds((const __attribute__((address_space(1))) void*)(gp), \
                                     (__attribute__((address_space(3))) void*)(lp), 16, 0, 0)

// ---------------------------------------------------------------------------
// K0+K1 merged: blocks [0,3072) = prep; blocks [3072,4096) = lifx.
// (unchanged — passed rounds 7-9)
// ---------------------------------------------------------------------------
__global__ __launch_bounds__(256)
void prep_lifx_kernel(
    const float* __restrict__ qw, const float* __restrict__ kw,
    const float* __restrict__ vw, const float* __restrict__ ow,
    const float* __restrict__ qg, const float* __restrict__ qb, const float* __restrict__ qm, const float* __restrict__ qv,
    const float* __restrict__ kg, const float* __restrict__ kb, const float* __restrict__ km, const float* __restrict__ kvr,
    const float* __restrict__ vg, const float* __restrict__ vb, const float* __restrict__ vm, const float* __restrict__ vv,
    const float* __restrict__ og, const float* __restrict__ ob, const float* __restrict__ om, const float* __restrict__ ov,
    const float* __restrict__ obias,
    ushort_t* __restrict__ wsplit, ushort_t* __restrict__ osplit,
    float* __restrict__ scale_qkv, float* __restrict__ shift_qkv,
    float* __restrict__ scale_o,   float* __restrict__ shift_o,
    float* __restrict__ kvpart,
    const float* __restrict__ x, ushort_t* __restrict__ xs)
{
    __shared__ ushort_t tile[64 * 66];
    const int bid = blockIdx.x;
    const int tid = threadIdx.x;

    if (bid < 3072) {
        int i = bid * 256 + tid;                 // [0, 1536*512)
        int d = i >> 9, c = i & 511;
        const float* src = (d < 512) ? qw : (d < 1024) ? kw : vw;
        float wv = src[(d & 511) * 512 + c];
        ushort_t h = f2bf(wv);
        float r1 = wv - bf2f(h);
        ushort_t mm = f2bf(r1);
        wsplit[((size_t)d * 2 + 0) * 512 + c] = h;
        wsplit[((size_t)d * 2 + 1) * 512 + c] = mm;
        if (d < 512)
            osplit[(size_t)d * 512 + c] = f2bf(ow[d * 512 + c]);

        if (i < 3 * C_) {
            int p = i >> 9, dl = i & 511;
            const float* g = (p == 0) ? qg : (p == 1) ? kg : vg;
            const float* b = (p == 0) ? qb : (p == 1) ? kb : vb;
            const float* m = (p == 0) ? qm : (p == 1) ? km : vm;
            const float* r = (p == 0) ? qv : (p == 1) ? kvr : vv;
            float sc = g[dl] / sqrtf(r[dl] + 1e-5f);
            scale_qkv[i] = sc;
            shift_qkv[i] = b[dl] - m[dl] * sc;
        }
        if (i < C_) {
            float sc = og[i] / sqrtf(ov[i] + 1e-5f);
            scale_o[i] = sc;
            shift_o[i] = ob[i] - om[i] * sc + obias[i] * sc;
        }
        if (i < TB_ * C_) kvpart[i] = 0.f;
        return;
    }

    const int l = bid - 3072;                    // [0, 1024)
    const int n0 = (l & 3) * 64;
    const int c0 = ((l >> 2) & 7) * 64;
    const int b  = l >> 5;
    const int j = tid & 63, w = tid >> 6;
    const bool nok = (n0 + j) < N_;
    float v[16];
#pragma unroll
    for (int r = 0; r < 16; ++r) v[r] = 0.f;
    for (int t = 0; t < T_; ++t) {
        const float* xb = x + ((size_t)((t * B_ + b) * C_ + c0)) * N_ + n0 + j;
#pragma unroll
        for (int r = 0; r < 16; ++r) {
            int i = w * 16 + r;
            float xv = nok ? xb[(size_t)i * N_] : 0.f;
            v[r] = v[r] + (xv - v[r]) * 0.5f;
            bool s = (v[r] >= 1.0f);
            tile[j * 66 + i] = s ? 0x3F80 : 0;
            if (s) v[r] = 0.f;
        }
        __syncthreads();
#pragma unroll
        for (int p = 0; p < 2; ++p) {
            int w2 = tid + p * 256;
            int jj = w2 >> 3, ck = w2 & 7;
            if (n0 + jj < N_) {
                const unsigned int* src = reinterpret_cast<const unsigned int*>(&tile[jj * 66 + ck * 8]);
                uint4 dv; dv.x = src[0]; dv.y = src[1]; dv.z = src[2]; dv.w = src[3];
                size_t mp = (size_t)(b * N_ + n0 + jj) * 4 + t;      // permuted row
                *reinterpret_cast<uint4*>(&xs[mp * 512 + c0 + ck * 8]) = dv;
            }
        }
        __syncthreads();
    }
}

// ---------------------------------------------------------------------------
// K2: qkv GEMM — round-7 structure verbatim; k/v planes emit 1-bit spike
// bitmasks via __ballot (unchanged from round 9 — passed, WRITE −54MB).
// ---------------------------------------------------------------------------
__global__ __launch_bounds__(512, 4)
void qkv_gemm_lif(const ushort_t* __restrict__ W, const ushort_t* __restrict__ X,
                  const float* __restrict__ scale, const float* __restrict__ shift,
                  ushort_t* __restrict__ qspk, float* __restrict__ out2,
                  unsigned* __restrict__ kbit, unsigned* __restrict__ vbit)
{
    const int id = blockIdx.x;
    const int xw = id & 7, local = id >> 3;      // local in [0,150)
    const int ml = local / 12, d_t = local - ml * 12;
    const int m_t = ml * 8 + xw;
    if (m_t >= 98) return;
    const int m0 = m_t * 256;                    // m' base (256-tile)
    const int d0 = d_t * 128;                    // global d in [0,1536)

    __shared__ ushort_t Xs[2][16 * 512];  // dbuf x 16 chunks of 1KB: [mb(8)][ks(2)]
    __shared__ ushort_t Ws[2][16 * 512];  // dbuf x 16 chunks: [s(2)][db(4)][ks(2)]
    const int tid = threadIdx.x, wid = tid >> 6, lane = tid & 63;
    const int mw = (wid & 3) * 64, dw = (wid >> 2) * 64;
    const int row32 = lane & 31, khalf = lane >> 5;

    f32x16 acc[2][2] = {};               // [i: m-block32][j: d-block32]

    auto STAGE = [&](int buf, int k0) {
        {   int q = wid, mb = q >> 1, ks = q & 1;
            const ushort_t* g = X + (size_t)(m0 + mb * 32 + row32) * 512 + k0 + ks * 16 + khalf * 8;
            GL2LDS(g, &Xs[buf][q * 512]);
        }
        {   int q = wid + 8, mb = q >> 1, ks = q & 1;
            const ushort_t* g = X + (size_t)(m0 + mb * 32 + row32) * 512 + k0 + ks * 16 + khalf * 8;
            GL2LDS(g, &Xs[buf][q * 512]);
        }
        {   int q = wid, s = q >> 3, rem = q & 7, db = rem >> 1, ks = rem & 1;
            const ushort_t* g = W + ((size_t)(d0 + db * 32 + row32) * 2 + s) * 512 + k0 + ks * 16 + khalf * 8;
            GL2LDS(g, &Ws[buf][q * 512]);
        }
        {   int q = wid + 8, s = q >> 3, rem = q & 7, db = rem >> 1, ks = rem & 1;
            const ushort_t* g = W + ((size_t)(d0 + db * 32 + row32) * 2 + s) * 512 + k0 + ks * 16 + khalf * 8;
            GL2LDS(g, &Ws[buf][q * 512]);
        }
    };

    STAGE(0, 0);
    __syncthreads();
    int cur = 0;

    for (int it = 0; it < 16; ++it) {
        if (it < 15) STAGE(cur ^ 1, (it + 1) * 32);

        __builtin_amdgcn_s_setprio(1);
#pragma unroll
        for (int ks = 0; ks < 2; ++ks) {
            bf16x8 xfr[2];
#pragma unroll
            for (int i = 0; i < 2; ++i)
                xfr[i] = *reinterpret_cast<const bf16x8*>(
                    &Xs[cur][(((mw >> 5) + i) * 2 + ks) * 512 + lane * 8]);
#pragma unroll
            for (int s = 0; s < 2; ++s)
#pragma unroll
                for (int j = 0; j < 2; ++j) {
                    bf16x8 wfr = *reinterpret_cast<const bf16x8*>(
                        &Ws[cur][(s * 8 + ((dw >> 5) + j) * 2 + ks) * 512 + lane * 8]);
#pragma unroll
                    for (int i = 0; i < 2; ++i)
                        acc[i][j] = __builtin_amdgcn_mfma_f32_32x32x16_bf16(xfr[i], wfr, acc[i][j], 0, 0, 0);
                }
        }
        __builtin_amdgcn_s_setprio(0);
        __syncthreads();
        cur ^= 1;
    }

    // epilogue: BN -> LIF over t (reg&3).
    const int p = d0 >> 9;
    const bool isQ = (p == 0), isV = (p == 2);
    unsigned* __restrict__ bitp = (p == 1) ? kbit : vbit;
#pragma unroll
    for (int j = 0; j < 2; ++j) {
        int d = d0 + dw + j * 32 + row32;
        float sc = scale[d], sh = shift[d];
        int dl = d & 511;
        int h = dl >> 6, hd = dl & 63;
        int cw = ((d0 & 511) + dw + j * 32) >> 5;    // uniform per wave: [0,16)
#pragma unroll
        for (int i = 0; i < 2; ++i) {
            int bnb = (m0 + mw + i * 32) >> 2;
            f32x16 a = acc[i][j];
#pragma unroll
            for (int g = 0; g < 4; ++g) {
                int bn = bnb + 2 * g + khalf;
                float p0 = fmaf(a[4 * g + 0], sc, sh);
                float p1 = fmaf(a[4 * g + 1], sc, sh);
                float p2 = fmaf(a[4 * g + 2], sc, sh);
                float p3 = fmaf(a[4 * g + 3], sc, sh);
                float v = p0 * 0.5f;
                bool s0 = (v >= 1.f); if (s0) v = 0.f;
                v = v + (p1 - v) * 0.5f;
                bool s1 = (v >= 1.f); if (s1) v = 0.f;
                v = v + (p2 - v) * 0.5f;
                bool s2 = (v >= 1.f); if (s2) v = 0.f;
                v = v + (p3 - v) * 0.5f;
                bool s3 = (v >= 1.f);

                if (isQ) {
                    ushort_t* b0 = qspk + (size_t)bn * 512 + dl;
                    b0[0]                      = s0 ? 0x3F80 : 0;
                    b0[(size_t)BNP_ * 512]     = s1 ? 0x3F80 : 0;
                    b0[(size_t)2 * BNP_ * 512] = s2 ? 0x3F80 : 0;
                    b0[(size_t)3 * BNP_ * 512] = s3 ? 0x3F80 : 0;
                } else {
                    const int bn_e = bnb + 2 * g;
                    bool sarr[4] = {s0, s1, s2, s3};
#pragma unroll
                    for (int t = 0; t < 4; ++t) {
                        unsigned long long bm = __ballot(sarr[t]);
                        if (lane == 0)
                            bitp[((size_t)t * BNP_ + bn_e) * 16 + cw] = (unsigned)bm;
                        else if (lane == 32)
                            bitp[((size_t)t * BNP_ + bn_e + 1) * 16 + cw] = (unsigned)(bm >> 32);
                    }
                    if (isV) {
                        int b = bn / N_, n = bn - b * N_;
                        float* o = out2 + (((size_t)b * 8 + h) * N_ + n) * 64 + hd;
                        o[0]                       = s0 ? 1.f : 0.f;
                        o[(size_t)1 * (OUT1_ / 4)] = s1 ? 1.f : 0.f;
                        o[(size_t)2 * (OUT1_ / 4)] = s2 ? 1.f : 0.f;
                        o[(size_t)3 * (OUT1_ / 4)] = s3 ? 1.f : 0.f;
                    }
                }
            }
        }
    }
}

// ---------------------------------------------------------------------------
// K3a: kv bit-count with REAL parallelism. grid 256 = (tb, half):
// block streams its half-row's k/v bitmask words (contiguous 98*16 words,
// 64B-aligned) as uint4, ANDs into LDS, then each thread extracts its
// channel's bit over 98 broadcast LDS reads and does ONE exact float
// atomicAdd (<=98, integer) into kvpart (zeroed by prep). 3.2MB coalesced
// global traffic total. Fixes round-9's 1-wave/CU latency disaster.
// ---------------------------------------------------------------------------
__global__ __launch_bounds__(256)
void kv_count_kernel(const unsigned* __restrict__ kbit, const unsigned* __restrict__ vbit,
                     float* __restrict__ kvpart)
{
    __shared__ unsigned andw[98 * 16];           // 6.3 KB
    const int tid = threadIdx.x;
    const int tb = blockIdx.x >> 1, half = blockIdx.x & 1;
    const int t = tb >> 5, b = tb & 31;
    const size_t wbase = ((size_t)t * BNP_ + (size_t)b * N_ + half * 98) * 16;

    const uint4* k4 = reinterpret_cast<const uint4*>(kbit + wbase);
    const uint4* v4 = reinterpret_cast<const uint4*>(vbit + wbase);
    for (int w = tid; w < 392; w += 256) {       // 392 uint4 = 1568 words
        uint4 kq = k4[w], vq = v4[w];
        uint4 aq; aq.x = kq.x & vq.x; aq.y = kq.y & vq.y;
        aq.z = kq.z & vq.z; aq.w = kq.w & vq.w;
        *reinterpret_cast<uint4*>(&andw[w * 4]) = aq;
    }
    __syncthreads();

#pragma unroll
    for (int u = 0; u < 2; ++u) {
        int c = tid + u * 256;
        int cw = c >> 5, bit = c & 31;
        int cnt = 0;
        for (int r = 0; r < 98; ++r)             // broadcast LDS reads
            cnt += (int)((andw[r * 16 + cw] >> bit) & 1u);
        if (cnt) atomicAdd(&kvpart[tb * 512 + c], (float)cnt);
    }
}

// ---------------------------------------------------------------------------
// K4: LIF over t on kvpart -> kv spikes bf16 [tb][c] (round-7 verbatim)
// ---------------------------------------------------------------------------
__global__ void kv_lif_kernel(const float* __restrict__ kvpart, ushort_t* __restrict__ kvs)
{
    int i = blockIdx.x * 256 + threadIdx.x;      // 32*512
    if (i >= B_ * C_) return;
    int b = i >> 9, c = i & 511;
    float v = 0.f;
#pragma unroll
    for (int t = 0; t < T_; ++t) {
        float y = kvpart[((t * B_ + b) << 9) + c];
        v = v + (y - v) * 0.5f;
        bool s = (v >= 1.f);
        kvs[((t * B_ + b) << 9) + c] = s ? 0x3F80 : 0;
        if (s) v = 0.f;
    }
}

// ---------------------------------------------------------------------------
// K6: out GEMM with fused muly (unchanged — passed rounds 7-9).
// ---------------------------------------------------------------------------
__global__ __launch_bounds__(256)
void out_gemm(const ushort_t* __restrict__ A, const ushort_t* __restrict__ qs,
              const ushort_t* __restrict__ kvs,
              const float* __restrict__ scale, const float* __restrict__ shift,
              const float* __restrict__ xid, float* __restrict__ out)
{
    const int id = blockIdx.x;
    const int xw = id & 7, local = id >> 3;      // local < 100
    const int m_t = (local >> 2) * 8 + xw, d_t = local & 3;
    if (m_t >= 196) return;
    const int m0 = m_t * 128, d0 = d_t * 128;

    __shared__ ushort_t As[2][8 * 512];  // dbuf x [db(4)][ks(2)]
    __shared__ ushort_t Bs[2][8 * 512];  // dbuf x [mb(4)][ks(2)]
    const int tid = threadIdx.x, wid = tid >> 6, lane = tid & 63;
    const int dw = (wid >> 1) * 64, mw = (wid & 1) * 64;
    const int row32 = lane & 31, khalf = lane >> 5;

    int sm[2], stb[2], sq[2], sL[2];
#pragma unroll
    for (int u = 0; u < 2; ++u) {
        int s = tid + u * 256;
        sq[u] = s >> 6; sL[u] = s & 63;
        sm[u] = m0 + (sq[u] >> 1) * 32 + (sL[u] & 31);
        stb[u] = sm[u] / N_;
    }

    f32x16 acc[2][2] = {};               // [i: d-block32][j: m-block32]

    {
        uint4 o[2];
#pragma unroll
        for (int u = 0; u < 2; ++u) {
            int kk = (sq[u] & 1) * 16 + (sL[u] >> 5) * 8;
            uint4 qv = *reinterpret_cast<const uint4*>(&qs[(size_t)sm[u] * 512 + kk]);
            uint4 kv = *reinterpret_cast<const uint4*>(&kvs[(size_t)stb[u] * 512 + kk]);
            o[u].x = qv.x & kv.x; o[u].y = qv.y & kv.y;
            o[u].z = qv.z & kv.z; o[u].w = qv.w & kv.w;
        }
        for (int q = wid; q < 8; q += 4) {
            int db = q >> 1, ks2 = q & 1;
            const ushort_t* g = A + (size_t)(d0 + db * 32 + row32) * 512 + ks2 * 16 + khalf * 8;
            GL2LDS(g, &As[0][q * 512]);
        }
#pragma unroll
        for (int u = 0; u < 2; ++u)
            *reinterpret_cast<uint4*>(&Bs[0][sq[u] * 512 + sL[u] * 8]) = o[u];
    }
    __syncthreads();

    int buf = 0;
    for (int it = 0; it < 16; ++it) {
        uint4 nq[2], nk[2];
        if (it < 15) {
            int k0n = (it + 1) * 32;
#pragma unroll
            for (int u = 0; u < 2; ++u) {
                int kk = k0n + (sq[u] & 1) * 16 + (sL[u] >> 5) * 8;
                nq[u] = *reinterpret_cast<const uint4*>(&qs[(size_t)sm[u] * 512 + kk]);
                nk[u] = *reinterpret_cast<const uint4*>(&kvs[(size_t)stb[u] * 512 + kk]);
            }
            for (int q = wid; q < 8; q += 4) {
                int db = q >> 1, ks2 = q & 1;
                const ushort_t* g = A + (size_t)(d0 + db * 32 + row32) * 512 + k0n + ks2 * 16 + khalf * 8;
                GL2LDS(g, &As[buf ^ 1][q * 512]);
            }
        }

        __builtin_amdgcn_s_setprio(1);
#pragma unroll
        for (int ks = 0; ks < 2; ++ks) {
            bf16x8 afr[2];
#pragma unroll
            for (int i = 0; i < 2; ++i)
                afr[i] = *reinterpret_cast<const bf16x8*>(
                    &As[buf][(((dw >> 5) + i) * 2 + ks) * 512 + lane * 8]);
#pragma unroll
            for (int j = 0; j < 2; ++j) {
                bf16x8 bfr = *reinterpret_cast<const bf16x8*>(
                    &Bs[buf][(((mw >> 5) + j) * 2 + ks) * 512 + lane * 8]);
#pragma unroll
                for (int i = 0; i < 2; ++i)
                    acc[i][j] = __builtin_amdgcn_mfma_f32_32x32x16_bf16(afr[i], bfr, acc[i][j], 0, 0, 0);
            }
        }
        __builtin_amdgcn_s_setprio(0);

        if (it < 15) {
#pragma unroll
            for (int u = 0; u < 2; ++u) {
                uint4 o;
                o.x = nq[u].x & nk[u].x; o.y = nq[u].y & nk[u].y;
                o.z = nq[u].z & nk[u].z; o.w = nq[u].w & nk[u].w;
                *reinterpret_cast<uint4*>(&Bs[buf ^ 1][sq[u] * 512 + sL[u] * 8]) = o;
            }
        }
        __syncthreads();
        buf ^= 1;
    }

#pragma unroll
    for (int j = 0; j < 2; ++j) {
        int m = m0 + mw + j * 32 + row32;
        int tb = m / N_;
        int n  = m - tb * N_;
        size_t mbase = (size_t)tb * (C_ * N_) + n;
#pragma unroll
        for (int i = 0; i < 2; ++i) {
            int dbase = d0 + dw + i * 32 + 4 * khalf;
            f32x16 a = acc[i][j];
#pragma unroll
            for (int g = 0; g < 4; ++g) {
#pragma unroll
                for (int t = 0; t < 4; ++t) {
                    int d = dbase + t + 8 * g;
                    float val = fmaf(a[4 * g + t], scale[d], shift[d]);
                    size_t ad = mbase + (size_t)d * N_;
                    out[ad] = val + xid[ad];
                }
            }
        }
    }
}

// ---------------------------------------------------------------------------
extern "C" void kernel_launch(void* const* d_in, const int* in_sizes, int n_in,
                              void* d_out, int out_size, void* d_ws, size_t ws_size,
                              hipStream_t stream)
{
    const float* x    = (const float*)d_in[0];
    const float* q_w  = (const float*)d_in[1];
    const float* k_w  = (const float*)d_in[2];
    const float* v_w  = (const float*)d_in[3];
    const float* o_w  = (const float*)d_in[4];
    const float* o_b  = (const float*)d_in[5];
    const float* qg = (const float*)d_in[6],  *qb = (const float*)d_in[7],
               *qm = (const float*)d_in[8],  *qv = (const float*)d_in[9];
    const float* kg = (const float*)d_in[10], *kb = (const float*)d_in[11],
               *km = (const float*)d_in[12], *kv = (const float*)d_in[13];
    const float* vg = (const float*)d_in[14], *vb = (const float*)d_in[15],
               *vm = (const float*)d_in[16], *vv = (const float*)d_in[17];
    const float* og = (const float*)d_in[18], *ob = (const float*)d_in[19],
               *om = (const float*)d_in[20], *ov = (const float*)d_in[21];

    float* out1  = (float*)d_out;
    float* out2f = out1 + OUT1_;

    // d_ws layout (k/v plane regions reused for bitmasks, 1.6 MB each)
    ushort_t* spk    = (ushort_t*)d_ws;                      // q: [M][512] bf16 spikes
    ushort_t* xs     = spk + (size_t)3 * M_ * 512;           // [M][512] bf16 (m' order)
    ushort_t* wsplit = xs + (size_t)M_ * 512;                // 1536*2*512
    ushort_t* osplit = wsplit + (size_t)1536 * 2 * 512;      // 512*512
    float*    kvpart = (float*)(osplit + (size_t)512 * 512); // [TB][C]
    ushort_t* kvs    = (ushort_t*)(kvpart + TB_ * C_);       // [TB][C]
    float*    scq    = (float*)(kvs + TB_ * C_);
    float*    shq    = scq + 3 * C_;
    float*    sco    = shq + 3 * C_;
    float*    sho    = sco + C_;

    ushort_t* qsp = spk;
    unsigned* kbit = (unsigned*)(spk + (size_t)M_ * 512);        // in old k-plane
    unsigned* vbit = (unsigned*)(spk + (size_t)2 * M_ * 512);    // in old v-plane

    prep_lifx_kernel<<<4096, 256, 0, stream>>>(
        q_w, k_w, v_w, o_w,
        qg, qb, qm, qv, kg, kb, km, kv, vg, vb, vm, vv, og, ob, om, ov, o_b,
        wsplit, osplit, scq, shq, sco, sho, kvpart, x, xs);

    qkv_gemm_lif<<<1200, 512, 0, stream>>>(wsplit, xs, scq, shq, qsp, out2f, kbit, vbit);

    kv_count_kernel<<<256, 256, 0, stream>>>(kbit, vbit, kvpart);

    kv_lif_kernel<<<64, 256, 0, stream>>>(kvpart, kvs);

    out_gemm<<<800, 256, 0, stream>>>(osplit, qsp, kvs, sco, sho, x, out1);
}